// Round 2
// baseline (885.390 us; speedup 1.0000x reference)
//
#include <hip/hip_runtime.h>
#include <hip/hip_bf16.h>
#include <cstdint>
#include <cstddef>

#define BB 16
#define NN 1024
#define DD 64
#define NHH 4
#define HDD 16
#define KSPL 8   // key splits for attention (128 keys per split)

// workspace layout (in floats)
#define OFF_Q  0
#define OFF_K  (OFF_Q + BB*NHH*NN*HDD)                   // 1,048,576 each
#define OFF_V  (OFF_K + BB*NHH*NN*HDD)
#define OFF_L  (OFF_V + BB*NHH*NN*HDD)                   // KSPL*64*1024
#define OFF_AT (OFF_L + KSPL*64*NN)
#define OFF_PM (OFF_AT + (size_t)KSPL*64*NN*HDD)
#define OFF_VM (OFF_PM + 1024)                            // 16*64*256*256 floats
#define NEED_FULL  ((size_t)(OFF_VM + (size_t)BB*DD*256*256) * 4)
#define NEED_FALLB ((size_t)(OFF_VM) * 4)

// ---------------------------------------------------------------------------
// A: fused horizontal 5-tap sum (zero-padded) + vertical inclusive prefix.
// One block per (b,c) plane; thread = x column; serial over y.
// V[y][x] = sum_{r<=y} sum_{dx=-2..2} fm[r][x+dx]
__global__ __launch_bounds__(256) void k_scanv(
    const float* __restrict__ fm, float* __restrict__ Vm)
{
    int plane = blockIdx.x;              // b*64 + c
    int x = threadIdx.x;
    const float* p = fm + ((size_t)plane << 16);
    float* o = Vm + ((size_t)plane << 16);
    float vacc = 0.f;
    #pragma unroll 4
    for (int y = 0; y < 256; ++y) {
        const float* row = p + (y << 8);
        float h = row[x];                               // L1-hot neighbors
        if (x >= 1)   h += row[x - 1];
        if (x >= 2)   h += row[x - 2];
        if (x <= 254) h += row[x + 1];
        if (x <= 253) h += row[x + 2];
        vacc += h;
        o[(y << 8) + x] = vacc;
    }
}

// ---------------------------------------------------------------------------
// B: patch means via 2-tap prefix difference + Q/K/V projections.
// 4 points per block (one wave each); lane = channel.
__global__ __launch_bounds__(256) void k_pf_qkv2(
    const float* __restrict__ desc, const float* __restrict__ Vm,
    const int* __restrict__ coords,
    const float* __restrict__ Wq, const float* __restrict__ bq,
    const float* __restrict__ Wk, const float* __restrict__ bk,
    const float* __restrict__ Wv, const float* __restrict__ bv,
    float* __restrict__ Q, float* __restrict__ K, float* __restrict__ V)
{
    int w   = threadIdx.x >> 6;
    int c   = threadIdx.x & 63;
    int pid = blockIdx.x * 4 + w;
    int b   = pid >> 10;
    int n   = pid & 1023;

    __shared__ float spf[4][64];
    __shared__ float sd[4][64];

    int y = coords[pid * 2 + 0];
    int x = coords[pid * 2 + 1];

    const float* vp = Vm + ((size_t)(b * 64 + c) << 16);
    int y2 = min(y + 2, 255);
    float v2 = vp[(y2 << 8) + x];
    float v1 = (y >= 3) ? vp[((y - 3) << 8) + x] : 0.f;
    spf[w][c] = (v2 - v1) * 0.04f;
    sd[w][c]  = desc[(size_t)pid * 64 + c];
    __syncthreads();

    float aq = bq[c], ak = bk[c], av = bv[c];
    #pragma unroll 8
    for (int i = 0; i < 64; ++i) {
        float xd = sd[w][i];
        float xp = spf[w][i];
        aq = fmaf(xd, Wq[i * 64 + c], aq);
        ak = fmaf(xp, Wk[i * 64 + c], ak);
        av = fmaf(xp, Wv[i * 64 + c], av);
    }
    int h = c >> 4, d = c & 15;
    size_t o = (((size_t)b * 4 + h) * 1024 + n) * 16 + d;   // (B,NH,N,hd)
    Q[o] = aq; K[o] = ak; V[o] = av;
}

// ---------------------------------------------------------------------------
// B-fallback: original 25-tap gather (used only if ws too small for V map).
__global__ __launch_bounds__(256) void k_pf_qkv(
    const float* __restrict__ desc, const float* __restrict__ fm,
    const int* __restrict__ coords,
    const float* __restrict__ Wq, const float* __restrict__ bq,
    const float* __restrict__ Wk, const float* __restrict__ bk,
    const float* __restrict__ Wv, const float* __restrict__ bv,
    float* __restrict__ Q, float* __restrict__ K, float* __restrict__ V)
{
    int w   = threadIdx.x >> 6;
    int c   = threadIdx.x & 63;
    int pid = blockIdx.x * 4 + w;
    int b   = pid >> 10;
    int n   = pid & 1023;

    __shared__ float spf[4][64];
    __shared__ float sd[4][64];

    int y = coords[pid * 2 + 0];
    int x = coords[pid * 2 + 1];

    const float* fmc = fm + ((size_t)(b * 64 + c) << 16);
    float s = 0.f;
    #pragma unroll
    for (int dy = -2; dy <= 2; ++dy) {
        int yy = y + dy;
        if ((unsigned)yy < 256u) {
            const float* row = fmc + yy * 256;
            #pragma unroll
            for (int dx = -2; dx <= 2; ++dx) {
                int xx = x + dx;
                if ((unsigned)xx < 256u) s += row[xx];
            }
        }
    }
    spf[w][c] = s * 0.04f;
    sd[w][c]  = desc[(size_t)pid * 64 + c];
    __syncthreads();

    float aq = bq[c], ak = bk[c], av = bv[c];
    #pragma unroll 8
    for (int i = 0; i < 64; ++i) {
        float xd = sd[w][i];
        float xp = spf[w][i];
        aq = fmaf(xd, Wq[i * 64 + c], aq);
        ak = fmaf(xp, Wk[i * 64 + c], ak);
        av = fmaf(xp, Wv[i * 64 + c], av);
    }
    int h = c >> 4, d = c & 15;
    size_t o = (((size_t)b * 4 + h) * 1024 + n) * 16 + d;
    Q[o] = aq; K[o] = ak; V[o] = av;
}

// ---------------------------------------------------------------------------
// K2: pm1[b][c] = 1 + (pose_embed @ Wp + bp)
__global__ __launch_bounds__(64) void k_pose(
    const float* __restrict__ pe, const float* __restrict__ Wp,
    const float* __restrict__ bp, float* __restrict__ pm1)
{
    int b = blockIdx.x, c = threadIdx.x;
    __shared__ float sp[64];
    sp[c] = pe[b * 64 + c];
    __syncthreads();
    float acc = bp[c];
    #pragma unroll 8
    for (int i = 0; i < 64; ++i) acc = fmaf(sp[i], Wp[i * 64 + c], acc);
    pm1[b * 64 + c] = 1.f + acc;
}

// ---------------------------------------------------------------------------
// K3: attention, shift-free softmax, LDS-staged K/V, split-K over 8 splits
// of 128 keys. Block = 256 threads; each thread owns 2 query rows.
// grid = 64bh * 2qt * 8s = 1024 blocks.
__global__ __launch_bounds__(256, 4) void k_attn2(
    const float* __restrict__ Q, const float* __restrict__ K,
    const float* __restrict__ V,
    float* __restrict__ lpart, float* __restrict__ apart)
{
    int idx = blockIdx.x;
    int s   = idx & 7;
    int qt  = (idx >> 3) & 1;
    int bh  = idx >> 4;                 // 0..63
    int t   = threadIdx.x;

    __shared__ float4 sK[128 * 4];
    __shared__ float4 sV[128 * 4];

    const float4* Kg = ((const float4*)K) + ((size_t)bh << 12) + ((size_t)s << 9);
    const float4* Vg = ((const float4*)V) + ((size_t)bh << 12) + ((size_t)s << 9);
    sK[t]       = Kg[t];
    sK[t + 256] = Kg[t + 256];
    sV[t]       = Vg[t];
    sV[t + 256] = Vg[t + 256];

    int r0 = qt * 512 + t;
    int r1 = r0 + 256;
    const float4* q0 = ((const float4*)Q) + (((size_t)bh << 10) + r0) * 4;
    const float4* q1 = ((const float4*)Q) + (((size_t)bh << 10) + r1) * 4;
    float4 q0a = q0[0], q0b = q0[1], q0c = q0[2], q0d = q0[3];
    float4 q1a = q1[0], q1b = q1[1], q1c = q1[2], q1d = q1[3];

    float4 A0 = {0,0,0,0}, A1 = {0,0,0,0}, A2 = {0,0,0,0}, A3 = {0,0,0,0};
    float4 B0 = {0,0,0,0}, B1 = {0,0,0,0}, B2 = {0,0,0,0}, B3 = {0,0,0,0};
    float l0 = 0.f, l1 = 0.f;

    __syncthreads();

    #pragma unroll 2
    for (int m = 0; m < 128; ++m) {
        float4 ka = sK[m*4+0], kb = sK[m*4+1], kc = sK[m*4+2], kd = sK[m*4+3];
        float4 va = sV[m*4+0], vb = sV[m*4+1], vc = sV[m*4+2], vd = sV[m*4+3];
        float s0 = q0a.x*ka.x + q0a.y*ka.y + q0a.z*ka.z + q0a.w*ka.w
                 + q0b.x*kb.x + q0b.y*kb.y + q0b.z*kb.z + q0b.w*kb.w
                 + q0c.x*kc.x + q0c.y*kc.y + q0c.z*kc.z + q0c.w*kc.w
                 + q0d.x*kd.x + q0d.y*kd.y + q0d.z*kd.z + q0d.w*kd.w;
        float s1 = q1a.x*ka.x + q1a.y*ka.y + q1a.z*ka.z + q1a.w*ka.w
                 + q1b.x*kb.x + q1b.y*kb.y + q1b.z*kb.z + q1b.w*kb.w
                 + q1c.x*kc.x + q1c.y*kc.y + q1c.z*kc.z + q1c.w*kc.w
                 + q1d.x*kd.x + q1d.y*kd.y + q1d.z*kd.z + q1d.w*kd.w;
        float p0 = __expf(s0 * 0.25f);   // scores bounded ~|3|: no max-shift
        float p1 = __expf(s1 * 0.25f);
        l0 += p0; l1 += p1;
        A0.x = fmaf(p0, va.x, A0.x); A0.y = fmaf(p0, va.y, A0.y);
        A0.z = fmaf(p0, va.z, A0.z); A0.w = fmaf(p0, va.w, A0.w);
        A1.x = fmaf(p0, vb.x, A1.x); A1.y = fmaf(p0, vb.y, A1.y);
        A1.z = fmaf(p0, vb.z, A1.z); A1.w = fmaf(p0, vb.w, A1.w);
        A2.x = fmaf(p0, vc.x, A2.x); A2.y = fmaf(p0, vc.y, A2.y);
        A2.z = fmaf(p0, vc.z, A2.z); A2.w = fmaf(p0, vc.w, A2.w);
        A3.x = fmaf(p0, vd.x, A3.x); A3.y = fmaf(p0, vd.y, A3.y);
        A3.z = fmaf(p0, vd.z, A3.z); A3.w = fmaf(p0, vd.w, A3.w);
        B0.x = fmaf(p1, va.x, B0.x); B0.y = fmaf(p1, va.y, B0.y);
        B0.z = fmaf(p1, va.z, B0.z); B0.w = fmaf(p1, va.w, B0.w);
        B1.x = fmaf(p1, vb.x, B1.x); B1.y = fmaf(p1, vb.y, B1.y);
        B1.z = fmaf(p1, vb.z, B1.z); B1.w = fmaf(p1, vb.w, B1.w);
        B2.x = fmaf(p1, vc.x, B2.x); B2.y = fmaf(p1, vc.y, B2.y);
        B2.z = fmaf(p1, vc.z, B2.z); B2.w = fmaf(p1, vc.w, B2.w);
        B3.x = fmaf(p1, vd.x, B3.x); B3.y = fmaf(p1, vd.y, B3.y);
        B3.z = fmaf(p1, vd.z, B3.z); B3.w = fmaf(p1, vd.w, B3.w);
    }

    size_t ro0 = (size_t)(s * 64 + bh) * 1024 + r0;
    size_t ro1 = (size_t)(s * 64 + bh) * 1024 + r1;
    lpart[ro0] = l0;
    lpart[ro1] = l1;
    float4* ap0 = (float4*)apart + ro0 * 4;
    float4* ap1 = (float4*)apart + ro1 * 4;
    ap0[0] = A0; ap0[1] = A1; ap0[2] = A2; ap0[3] = A3;
    ap1[0] = B0; ap1[1] = B1; ap1[2] = B2; ap1[3] = B3;
}

// ---------------------------------------------------------------------------
// K4: combine split-K partials, softmax divide, pose modulation, @ Wo + bo.
__global__ __launch_bounds__(256) void k_out(
    const float* __restrict__ lpart, const float* __restrict__ apart,
    const float* __restrict__ pm1, const float* __restrict__ Wo,
    const float* __restrict__ bo, float* __restrict__ out)
{
    int w   = threadIdx.x >> 6;
    int c   = threadIdx.x & 63;
    int pid = blockIdx.x * 4 + w;
    int b   = pid >> 10;
    int n   = pid & 1023;
    int h   = c >> 4, d = c & 15;
    int bh  = b * 4 + h;

    __shared__ float sf[4][64];

    float a = 0.f, ls = 0.f;
    #pragma unroll
    for (int s = 0; s < KSPL; ++s) {
        size_t ro = (size_t)(s * 64 + bh) * 1024 + n;
        a  += apart[(ro << 4) + d];
        ls += lpart[ro];
    }
    sf[w][c] = (a / ls) * pm1[b * 64 + c];
    __syncthreads();

    float acc = bo[c];
    #pragma unroll 8
    for (int i = 0; i < 64; ++i) acc = fmaf(sf[w][i], Wo[i * 64 + c], acc);
    out[(size_t)pid * 64 + c] = acc;
}

// ---------------------------------------------------------------------------
extern "C" void kernel_launch(void* const* d_in, const int* in_sizes, int n_in,
                              void* d_out, int out_size, void* d_ws, size_t ws_size,
                              hipStream_t stream)
{
    const float* desc = (const float*)d_in[0];
    const float* fm   = (const float*)d_in[1];
    const int*   crd  = (const int*)  d_in[2];
    const float* pe   = (const float*)d_in[3];
    const float* Wq   = (const float*)d_in[4];
    const float* bq   = (const float*)d_in[5];
    const float* Wk   = (const float*)d_in[6];
    const float* bk   = (const float*)d_in[7];
    const float* Wv   = (const float*)d_in[8];
    const float* bv   = (const float*)d_in[9];
    const float* Wp   = (const float*)d_in[10];
    const float* bp   = (const float*)d_in[11];
    const float* Wo   = (const float*)d_in[12];
    const float* bo   = (const float*)d_in[13];
    float* out = (float*)d_out;

    float* ws    = (float*)d_ws;
    float* Qb    = ws + OFF_Q;
    float* Kb    = ws + OFF_K;
    float* Vb    = ws + OFF_V;
    float* lpart = ws + OFF_L;
    float* apart = ws + OFF_AT;
    float* pm1   = ws + OFF_PM;
    float* Vm    = ws + OFF_VM;

    if (ws_size >= NEED_FULL) {
        // A: H+V prefix scan (streaming) then 2-tap gather + QKV.
        hipLaunchKernelGGL(k_scanv, dim3(BB * DD), dim3(256), 0, stream, fm, Vm);
        hipLaunchKernelGGL(k_pf_qkv2, dim3(BB * NN / 4), dim3(256), 0, stream,
                           desc, Vm, crd, Wq, bq, Wk, bk, Wv, bv, Qb, Kb, Vb);
    } else {
        hipLaunchKernelGGL(k_pf_qkv, dim3(BB * NN / 4), dim3(256), 0, stream,
                           desc, fm, crd, Wq, bq, Wk, bk, Wv, bv, Qb, Kb, Vb);
    }
    hipLaunchKernelGGL(k_pose, dim3(BB), dim3(64), 0, stream, pe, Wp, bp, pm1);
    hipLaunchKernelGGL(k_attn2, dim3(64 * 2 * KSPL), dim3(256), 0, stream,
                       Qb, Kb, Vb, lpart, apart);
    hipLaunchKernelGGL(k_out, dim3(BB * NN / 4), dim3(256), 0, stream,
                       lpart, apart, pm1, Wo, bo, out);
}

// Round 3
// 649.247 us; speedup vs baseline: 1.3637x; 1.3637x over previous
//
#include <hip/hip_runtime.h>
#include <hip/hip_bf16.h>
#include <cstdint>
#include <cstddef>

#define BB 16
#define NN 1024
#define DD 64
#define NHH 4
#define HDD 16
#define KSPL 8   // key splits for attention (128 keys per split)

// workspace layout (in floats)
#define OFF_Q  0
#define OFF_K  (OFF_Q + BB*NHH*NN*HDD)                   // 1,048,576 each
#define OFF_V  (OFF_K + BB*NHH*NN*HDD)
#define OFF_L  (OFF_V + BB*NHH*NN*HDD)                   // KSPL*64*1024
#define OFF_AT (OFF_L + KSPL*64*NN)
#define OFF_PM (OFF_AT + (size_t)KSPL*64*NN*HDD)
#define OFF_VM (OFF_PM + 1024)                            // 16*64*256*256 floats
#define NEED_FULL  ((size_t)(OFF_VM + (size_t)BB*DD*256*256) * 4)

// ---------------------------------------------------------------------------
// A: pure vertical inclusive prefix per (b,c) plane. 64 threads, float4/thread.
// No conditionals, no LDS, no barriers -> deep pipelining. V[y][x]=sum_{r<=y}fm[r][x]
__global__ __launch_bounds__(64) void k_scanv2(
    const float* __restrict__ fm, float* __restrict__ Vm)
{
    int plane = blockIdx.x;              // b*64 + c
    int t = threadIdx.x;                 // float4 column group
    const float4* p = (const float4*)(fm + ((size_t)plane << 16)) + t;
    float4*       o = (float4*)(Vm + ((size_t)plane << 16)) + t;
    float4 v = {0.f, 0.f, 0.f, 0.f};
    #pragma unroll 8
    for (int y = 0; y < 256; ++y) {
        float4 r = p[y << 6];            // row stride = 64 float4
        v.x += r.x; v.y += r.y; v.z += r.z; v.w += r.w;
        o[y << 6] = v;
    }
}

// ---------------------------------------------------------------------------
// B: patch means via vertical-prefix difference (2 rows) x horizontal 5 taps,
// then Q/K/V projections. 4 points/block (wave each); lane = channel.
// Coords are point-uniform -> all bounds branches are wave-uniform.
__global__ __launch_bounds__(256) void k_pf_qkv3(
    const float* __restrict__ desc, const float* __restrict__ Vm,
    const int* __restrict__ coords,
    const float* __restrict__ Wq, const float* __restrict__ bq,
    const float* __restrict__ Wk, const float* __restrict__ bk,
    const float* __restrict__ Wv, const float* __restrict__ bv,
    float* __restrict__ Q, float* __restrict__ K, float* __restrict__ V)
{
    int w   = threadIdx.x >> 6;
    int c   = threadIdx.x & 63;
    int pid = blockIdx.x * 4 + w;
    int b   = pid >> 10;
    int n   = pid & 1023;

    __shared__ float spf[4][64];
    __shared__ float sd[4][64];

    int y = coords[pid * 2 + 0];
    int x = coords[pid * 2 + 1];

    const float* vp = Vm + ((size_t)(b * 64 + c) << 16);
    int y2 = min(y + 2, 255);
    const float* r2 = vp + (y2 << 8);
    float s2 = r2[x];
    if (x >= 1)   s2 += r2[x - 1];
    if (x >= 2)   s2 += r2[x - 2];
    if (x <= 254) s2 += r2[x + 1];
    if (x <= 253) s2 += r2[x + 2];
    float s1 = 0.f;
    if (y >= 3) {
        const float* r1 = vp + ((y - 3) << 8);
        s1 = r1[x];
        if (x >= 1)   s1 += r1[x - 1];
        if (x >= 2)   s1 += r1[x - 2];
        if (x <= 254) s1 += r1[x + 1];
        if (x <= 253) s1 += r1[x + 2];
    }
    spf[w][c] = (s2 - s1) * 0.04f;
    sd[w][c]  = desc[(size_t)pid * 64 + c];
    __syncthreads();

    float aq = bq[c], ak = bk[c], av = bv[c];
    #pragma unroll 8
    for (int i = 0; i < 64; ++i) {
        float xd = sd[w][i];
        float xp = spf[w][i];
        aq = fmaf(xd, Wq[i * 64 + c], aq);
        ak = fmaf(xp, Wk[i * 64 + c], ak);
        av = fmaf(xp, Wv[i * 64 + c], av);
    }
    int h = c >> 4, d = c & 15;
    size_t o = (((size_t)b * 4 + h) * 1024 + n) * 16 + d;   // (B,NH,N,hd)
    Q[o] = aq; K[o] = ak; V[o] = av;
}

// ---------------------------------------------------------------------------
// B-fallback: original 25-tap gather (used only if ws too small for V map).
__global__ __launch_bounds__(256) void k_pf_qkv(
    const float* __restrict__ desc, const float* __restrict__ fm,
    const int* __restrict__ coords,
    const float* __restrict__ Wq, const float* __restrict__ bq,
    const float* __restrict__ Wk, const float* __restrict__ bk,
    const float* __restrict__ Wv, const float* __restrict__ bv,
    float* __restrict__ Q, float* __restrict__ K, float* __restrict__ V)
{
    int w   = threadIdx.x >> 6;
    int c   = threadIdx.x & 63;
    int pid = blockIdx.x * 4 + w;
    int b   = pid >> 10;
    int n   = pid & 1023;

    __shared__ float spf[4][64];
    __shared__ float sd[4][64];

    int y = coords[pid * 2 + 0];
    int x = coords[pid * 2 + 1];

    const float* fmc = fm + ((size_t)(b * 64 + c) << 16);
    float s = 0.f;
    #pragma unroll
    for (int dy = -2; dy <= 2; ++dy) {
        int yy = y + dy;
        if ((unsigned)yy < 256u) {
            const float* row = fmc + yy * 256;
            #pragma unroll
            for (int dx = -2; dx <= 2; ++dx) {
                int xx = x + dx;
                if ((unsigned)xx < 256u) s += row[xx];
            }
        }
    }
    spf[w][c] = s * 0.04f;
    sd[w][c]  = desc[(size_t)pid * 64 + c];
    __syncthreads();

    float aq = bq[c], ak = bk[c], av = bv[c];
    #pragma unroll 8
    for (int i = 0; i < 64; ++i) {
        float xd = sd[w][i];
        float xp = spf[w][i];
        aq = fmaf(xd, Wq[i * 64 + c], aq);
        ak = fmaf(xp, Wk[i * 64 + c], ak);
        av = fmaf(xp, Wv[i * 64 + c], av);
    }
    int h = c >> 4, d = c & 15;
    size_t o = (((size_t)b * 4 + h) * 1024 + n) * 16 + d;
    Q[o] = aq; K[o] = ak; V[o] = av;
}

// ---------------------------------------------------------------------------
// K2: pm1[b][c] = 1 + (pose_embed @ Wp + bp)
__global__ __launch_bounds__(64) void k_pose(
    const float* __restrict__ pe, const float* __restrict__ Wp,
    const float* __restrict__ bp, float* __restrict__ pm1)
{
    int b = blockIdx.x, c = threadIdx.x;
    __shared__ float sp[64];
    sp[c] = pe[b * 64 + c];
    __syncthreads();
    float acc = bp[c];
    #pragma unroll 8
    for (int i = 0; i < 64; ++i) acc = fmaf(sp[i], Wp[i * 64 + c], acc);
    pm1[b * 64 + c] = 1.f + acc;
}

// ---------------------------------------------------------------------------
// K3: attention, shift-free softmax. 4 query rows per thread; K/V rows read
// with wave-uniform addresses (scalarizable, no LDS). grid = 64bh*8s = 512.
__global__ __launch_bounds__(256, 2) void k_attn3(
    const float* __restrict__ Q, const float* __restrict__ K,
    const float* __restrict__ V,
    float* __restrict__ lpart, float* __restrict__ apart)
{
    int s  = blockIdx.x & 7;
    int bh = blockIdx.x >> 3;            // 0..63
    int t  = threadIdx.x;

    const float4* Kb = ((const float4*)K) + ((size_t)bh << 12) + ((size_t)s << 9);
    const float4* Vb = ((const float4*)V) + ((size_t)bh << 12) + ((size_t)s << 9);

    float4 q[4][4];
    float4 A[4][4];
    float  l[4];
    #pragma unroll
    for (int i = 0; i < 4; ++i) {
        const float4* qp = ((const float4*)Q) + (((size_t)bh << 10) + t + 256 * i) * 4;
        #pragma unroll
        for (int j = 0; j < 4; ++j) { q[i][j] = qp[j]; A[i][j] = make_float4(0.f,0.f,0.f,0.f); }
        l[i] = 0.f;
    }

    for (int m = 0; m < 128; ++m) {
        float4 ka = Kb[m*4+0], kb = Kb[m*4+1], kc = Kb[m*4+2], kd = Kb[m*4+3];
        float4 va = Vb[m*4+0], vb = Vb[m*4+1], vc = Vb[m*4+2], vd = Vb[m*4+3];
        #pragma unroll
        for (int i = 0; i < 4; ++i) {
            float sc = q[i][0].x*ka.x + q[i][0].y*ka.y + q[i][0].z*ka.z + q[i][0].w*ka.w
                     + q[i][1].x*kb.x + q[i][1].y*kb.y + q[i][1].z*kb.z + q[i][1].w*kb.w
                     + q[i][2].x*kc.x + q[i][2].y*kc.y + q[i][2].z*kc.z + q[i][2].w*kc.w
                     + q[i][3].x*kd.x + q[i][3].y*kd.y + q[i][3].z*kd.z + q[i][3].w*kd.w;
            float p = __expf(sc * 0.25f);     // scores bounded ~|3|: no max-shift
            l[i] += p;
            A[i][0].x = fmaf(p, va.x, A[i][0].x); A[i][0].y = fmaf(p, va.y, A[i][0].y);
            A[i][0].z = fmaf(p, va.z, A[i][0].z); A[i][0].w = fmaf(p, va.w, A[i][0].w);
            A[i][1].x = fmaf(p, vb.x, A[i][1].x); A[i][1].y = fmaf(p, vb.y, A[i][1].y);
            A[i][1].z = fmaf(p, vb.z, A[i][1].z); A[i][1].w = fmaf(p, vb.w, A[i][1].w);
            A[i][2].x = fmaf(p, vc.x, A[i][2].x); A[i][2].y = fmaf(p, vc.y, A[i][2].y);
            A[i][2].z = fmaf(p, vc.z, A[i][2].z); A[i][2].w = fmaf(p, vc.w, A[i][2].w);
            A[i][3].x = fmaf(p, vd.x, A[i][3].x); A[i][3].y = fmaf(p, vd.y, A[i][3].y);
            A[i][3].z = fmaf(p, vd.z, A[i][3].z); A[i][3].w = fmaf(p, vd.w, A[i][3].w);
        }
    }

    #pragma unroll
    for (int i = 0; i < 4; ++i) {
        size_t ro = (size_t)(s * 64 + bh) * 1024 + (t + 256 * i);
        lpart[ro] = l[i];
        float4* ap = (float4*)apart + ro * 4;
        ap[0] = A[i][0]; ap[1] = A[i][1]; ap[2] = A[i][2]; ap[3] = A[i][3];
    }
}

// ---------------------------------------------------------------------------
// K4: combine split-K partials, softmax divide, pose modulation, @ Wo + bo.
__global__ __launch_bounds__(256) void k_out(
    const float* __restrict__ lpart, const float* __restrict__ apart,
    const float* __restrict__ pm1, const float* __restrict__ Wo,
    const float* __restrict__ bo, float* __restrict__ out)
{
    int w   = threadIdx.x >> 6;
    int c   = threadIdx.x & 63;
    int pid = blockIdx.x * 4 + w;
    int b   = pid >> 10;
    int n   = pid & 1023;
    int h   = c >> 4, d = c & 15;
    int bh  = b * 4 + h;

    __shared__ float sf[4][64];

    float a = 0.f, ls = 0.f;
    #pragma unroll
    for (int s = 0; s < KSPL; ++s) {
        size_t ro = (size_t)(s * 64 + bh) * 1024 + n;
        a  += apart[(ro << 4) + d];
        ls += lpart[ro];
    }
    sf[w][c] = (a / ls) * pm1[b * 64 + c];
    __syncthreads();

    float acc = bo[c];
    #pragma unroll 8
    for (int i = 0; i < 64; ++i) acc = fmaf(sf[w][i], Wo[i * 64 + c], acc);
    out[(size_t)pid * 64 + c] = acc;
}

// ---------------------------------------------------------------------------
extern "C" void kernel_launch(void* const* d_in, const int* in_sizes, int n_in,
                              void* d_out, int out_size, void* d_ws, size_t ws_size,
                              hipStream_t stream)
{
    const float* desc = (const float*)d_in[0];
    const float* fm   = (const float*)d_in[1];
    const int*   crd  = (const int*)  d_in[2];
    const float* pe   = (const float*)d_in[3];
    const float* Wq   = (const float*)d_in[4];
    const float* bq   = (const float*)d_in[5];
    const float* Wk   = (const float*)d_in[6];
    const float* bk   = (const float*)d_in[7];
    const float* Wv   = (const float*)d_in[8];
    const float* bv   = (const float*)d_in[9];
    const float* Wp   = (const float*)d_in[10];
    const float* bp   = (const float*)d_in[11];
    const float* Wo   = (const float*)d_in[12];
    const float* bo   = (const float*)d_in[13];
    float* out = (float*)d_out;

    float* ws    = (float*)d_ws;
    float* Qb    = ws + OFF_Q;
    float* Kb    = ws + OFF_K;
    float* Vb    = ws + OFF_V;
    float* lpart = ws + OFF_L;
    float* apart = ws + OFF_AT;
    float* pm1   = ws + OFF_PM;
    float* Vm    = ws + OFF_VM;

    if (ws_size >= NEED_FULL) {
        hipLaunchKernelGGL(k_scanv2, dim3(BB * DD), dim3(64), 0, stream, fm, Vm);
        hipLaunchKernelGGL(k_pf_qkv3, dim3(BB * NN / 4), dim3(256), 0, stream,
                           desc, Vm, crd, Wq, bq, Wk, bk, Wv, bv, Qb, Kb, Vb);
    } else {
        hipLaunchKernelGGL(k_pf_qkv, dim3(BB * NN / 4), dim3(256), 0, stream,
                           desc, fm, crd, Wq, bq, Wk, bk, Wv, bv, Qb, Kb, Vb);
    }
    hipLaunchKernelGGL(k_pose, dim3(BB), dim3(64), 0, stream, pe, Wp, bp, pm1);
    hipLaunchKernelGGL(k_attn3, dim3(64 * KSPL), dim3(256), 0, stream,
                       Qb, Kb, Vb, lpart, apart);
    hipLaunchKernelGGL(k_out, dim3(BB * NN / 4), dim3(256), 0, stream,
                       lpart, apart, pm1, Wo, bo, out);
}

// Round 4
// 620.351 us; speedup vs baseline: 1.4272x; 1.0466x over previous
//
#include <hip/hip_runtime.h>
#include <hip/hip_bf16.h>
#include <cstdint>
#include <cstddef>

#define BB 16
#define NN 1024
#define DD 64
#define NHH 4
#define HDD 16
#define KSPL 8   // key splits for attention (128 keys per split)

// workspace layout (in floats)
#define OFF_Q  0
#define OFF_K  (OFF_Q + BB*NHH*NN*HDD)                   // 1,048,576 each
#define OFF_V  (OFF_K + BB*NHH*NN*HDD)
#define OFF_L  (OFF_V + BB*NHH*NN*HDD)                   // KSPL*64*1024
#define OFF_AT (OFF_L + KSPL*64*NN)
#define OFF_PM (OFF_AT + (size_t)KSPL*64*NN*HDD)
#define OFF_TP (OFF_PM + 1024)                            // 16*256*256*64 floats
#define NEED_FULL  ((size_t)(OFF_TP + (size_t)BB*256*256*DD) * 4)

// ---------------------------------------------------------------------------
// A: transpose fm (B,C,H,W) -> TP (B,H,W,C), pixel-major. Fully parallel.
// Block = 256 thr: c = t>>2 (64 channels), x4 = t&3 (4 float4 x-groups).
// Reads: float4, 16 full lines/wave-instr. Writes: 4 dword stores/thread,
// 4 full 64B lines per wave-instr (16 lanes of consecutive c per pixel-line).
__global__ __launch_bounds__(256) void k_tpose(
    const float* __restrict__ fm, float* __restrict__ TP)
{
    int t  = threadIdx.x;
    int c  = t >> 2, x4 = t & 3;
    int bid = blockIdx.x;                 // b*256 + yt*16 + xt
    int xt = bid & 15, yt = (bid >> 4) & 15, b = bid >> 8;
    int x0 = (xt << 4) + (x4 << 2);

    const float* src = fm + ((size_t)(b * 64 + c) << 16) + x0;
    float* dst = TP + ((size_t)b << 22) + ((size_t)x0 << 6) + c;

    #pragma unroll
    for (int yy = 0; yy < 16; ++yy) {
        int y = (yt << 4) + yy;
        float4 r = *(const float4*)(src + ((size_t)y << 8));
        float* d = dst + ((size_t)y << 14);
        d[0] = r.x; d[64] = r.y; d[128] = r.z; d[192] = r.w;
    }
}

// ---------------------------------------------------------------------------
// B: 25-tap patch mean from pixel-major TP (coalesced: lane = channel, one
// pixel = 256B contiguous) + Q/K/V projections. 4 points/block (wave each).
// Coords are point-uniform -> bounds branches wave-uniform.
__global__ __launch_bounds__(256) void k_pf_qkv4(
    const float* __restrict__ desc, const float* __restrict__ TP,
    const int* __restrict__ coords,
    const float* __restrict__ Wq, const float* __restrict__ bq,
    const float* __restrict__ Wk, const float* __restrict__ bk,
    const float* __restrict__ Wv, const float* __restrict__ bv,
    float* __restrict__ Q, float* __restrict__ K, float* __restrict__ V)
{
    int w   = threadIdx.x >> 6;
    int c   = threadIdx.x & 63;
    int pid = blockIdx.x * 4 + w;
    int b   = pid >> 10;
    int n   = pid & 1023;

    __shared__ float spf[4][64];
    __shared__ float sd[4][64];

    int y = coords[pid * 2 + 0];
    int x = coords[pid * 2 + 1];

    const float* tp = TP + ((size_t)b << 22) + c;
    float s = 0.f;
    #pragma unroll
    for (int dy = -2; dy <= 2; ++dy) {
        int yy = y + dy;
        if ((unsigned)yy < 256u) {
            const float* rp = tp + ((size_t)yy << 14);
            #pragma unroll
            for (int dx = -2; dx <= 2; ++dx) {
                int xx = x + dx;
                if ((unsigned)xx < 256u) s += rp[(size_t)xx << 6];
            }
        }
    }
    spf[w][c] = s * 0.04f;
    sd[w][c]  = desc[(size_t)pid * 64 + c];
    __syncthreads();

    float aq = bq[c], ak = bk[c], av = bv[c];
    #pragma unroll 8
    for (int i = 0; i < 64; ++i) {
        float xd = sd[w][i];
        float xp = spf[w][i];
        aq = fmaf(xd, Wq[i * 64 + c], aq);
        ak = fmaf(xp, Wk[i * 64 + c], ak);
        av = fmaf(xp, Wv[i * 64 + c], av);
    }
    int h = c >> 4, d = c & 15;
    size_t o = (((size_t)b * 4 + h) * 1024 + n) * 16 + d;   // (B,NH,N,hd)
    Q[o] = aq; K[o] = ak; V[o] = av;
}

// ---------------------------------------------------------------------------
// B-fallback: original 25-tap gather from channel-major fm (ws too small).
__global__ __launch_bounds__(256) void k_pf_qkv(
    const float* __restrict__ desc, const float* __restrict__ fm,
    const int* __restrict__ coords,
    const float* __restrict__ Wq, const float* __restrict__ bq,
    const float* __restrict__ Wk, const float* __restrict__ bk,
    const float* __restrict__ Wv, const float* __restrict__ bv,
    float* __restrict__ Q, float* __restrict__ K, float* __restrict__ V)
{
    int w   = threadIdx.x >> 6;
    int c   = threadIdx.x & 63;
    int pid = blockIdx.x * 4 + w;
    int b   = pid >> 10;
    int n   = pid & 1023;

    __shared__ float spf[4][64];
    __shared__ float sd[4][64];

    int y = coords[pid * 2 + 0];
    int x = coords[pid * 2 + 1];

    const float* fmc = fm + ((size_t)(b * 64 + c) << 16);
    float s = 0.f;
    #pragma unroll
    for (int dy = -2; dy <= 2; ++dy) {
        int yy = y + dy;
        if ((unsigned)yy < 256u) {
            const float* row = fmc + yy * 256;
            #pragma unroll
            for (int dx = -2; dx <= 2; ++dx) {
                int xx = x + dx;
                if ((unsigned)xx < 256u) s += row[xx];
            }
        }
    }
    spf[w][c] = s * 0.04f;
    sd[w][c]  = desc[(size_t)pid * 64 + c];
    __syncthreads();

    float aq = bq[c], ak = bk[c], av = bv[c];
    #pragma unroll 8
    for (int i = 0; i < 64; ++i) {
        float xd = sd[w][i];
        float xp = spf[w][i];
        aq = fmaf(xd, Wq[i * 64 + c], aq);
        ak = fmaf(xp, Wk[i * 64 + c], ak);
        av = fmaf(xp, Wv[i * 64 + c], av);
    }
    int h = c >> 4, d = c & 15;
    size_t o = (((size_t)b * 4 + h) * 1024 + n) * 16 + d;
    Q[o] = aq; K[o] = ak; V[o] = av;
}

// ---------------------------------------------------------------------------
// K2: pm1[b][c] = 1 + (pose_embed @ Wp + bp)
__global__ __launch_bounds__(64) void k_pose(
    const float* __restrict__ pe, const float* __restrict__ Wp,
    const float* __restrict__ bp, float* __restrict__ pm1)
{
    int b = blockIdx.x, c = threadIdx.x;
    __shared__ float sp[64];
    sp[c] = pe[b * 64 + c];
    __syncthreads();
    float acc = bp[c];
    #pragma unroll 8
    for (int i = 0; i < 64; ++i) acc = fmaf(sp[i], Wp[i * 64 + c], acc);
    pm1[b * 64 + c] = 1.f + acc;
}

// ---------------------------------------------------------------------------
// K3: attention, shift-free softmax. 4 query rows per thread; K/V rows read
// with wave-uniform addresses (scalarizable, no LDS). grid = 64bh*8s = 512.
__global__ __launch_bounds__(256, 2) void k_attn3(
    const float* __restrict__ Q, const float* __restrict__ K,
    const float* __restrict__ V,
    float* __restrict__ lpart, float* __restrict__ apart)
{
    int s  = blockIdx.x & 7;
    int bh = blockIdx.x >> 3;            // 0..63
    int t  = threadIdx.x;

    const float4* Kb = ((const float4*)K) + ((size_t)bh << 12) + ((size_t)s << 9);
    const float4* Vb = ((const float4*)V) + ((size_t)bh << 12) + ((size_t)s << 9);

    float4 q[4][4];
    float4 A[4][4];
    float  l[4];
    #pragma unroll
    for (int i = 0; i < 4; ++i) {
        const float4* qp = ((const float4*)Q) + (((size_t)bh << 10) + t + 256 * i) * 4;
        #pragma unroll
        for (int j = 0; j < 4; ++j) { q[i][j] = qp[j]; A[i][j] = make_float4(0.f,0.f,0.f,0.f); }
        l[i] = 0.f;
    }

    for (int m = 0; m < 128; ++m) {
        float4 ka = Kb[m*4+0], kb = Kb[m*4+1], kc = Kb[m*4+2], kd = Kb[m*4+3];
        float4 va = Vb[m*4+0], vb = Vb[m*4+1], vc = Vb[m*4+2], vd = Vb[m*4+3];
        #pragma unroll
        for (int i = 0; i < 4; ++i) {
            float sc = q[i][0].x*ka.x + q[i][0].y*ka.y + q[i][0].z*ka.z + q[i][0].w*ka.w
                     + q[i][1].x*kb.x + q[i][1].y*kb.y + q[i][1].z*kb.z + q[i][1].w*kb.w
                     + q[i][2].x*kc.x + q[i][2].y*kc.y + q[i][2].z*kc.z + q[i][2].w*kc.w
                     + q[i][3].x*kd.x + q[i][3].y*kd.y + q[i][3].z*kd.z + q[i][3].w*kd.w;
            float p = __expf(sc * 0.25f);     // scores bounded ~|3|: no max-shift
            l[i] += p;
            A[i][0].x = fmaf(p, va.x, A[i][0].x); A[i][0].y = fmaf(p, va.y, A[i][0].y);
            A[i][0].z = fmaf(p, va.z, A[i][0].z); A[i][0].w = fmaf(p, va.w, A[i][0].w);
            A[i][1].x = fmaf(p, vb.x, A[i][1].x); A[i][1].y = fmaf(p, vb.y, A[i][1].y);
            A[i][1].z = fmaf(p, vb.z, A[i][1].z); A[i][1].w = fmaf(p, vb.w, A[i][1].w);
            A[i][2].x = fmaf(p, vc.x, A[i][2].x); A[i][2].y = fmaf(p, vc.y, A[i][2].y);
            A[i][2].z = fmaf(p, vc.z, A[i][2].z); A[i][2].w = fmaf(p, vc.w, A[i][2].w);
            A[i][3].x = fmaf(p, vd.x, A[i][3].x); A[i][3].y = fmaf(p, vd.y, A[i][3].y);
            A[i][3].z = fmaf(p, vd.z, A[i][3].z); A[i][3].w = fmaf(p, vd.w, A[i][3].w);
        }
    }

    #pragma unroll
    for (int i = 0; i < 4; ++i) {
        size_t ro = (size_t)(s * 64 + bh) * 1024 + (t + 256 * i);
        lpart[ro] = l[i];
        float4* ap = (float4*)apart + ro * 4;
        ap[0] = A[i][0]; ap[1] = A[i][1]; ap[2] = A[i][2]; ap[3] = A[i][3];
    }
}

// ---------------------------------------------------------------------------
// K4: combine split-K partials, softmax divide, pose modulation, @ Wo + bo.
__global__ __launch_bounds__(256) void k_out(
    const float* __restrict__ lpart, const float* __restrict__ apart,
    const float* __restrict__ pm1, const float* __restrict__ Wo,
    const float* __restrict__ bo, float* __restrict__ out)
{
    int w   = threadIdx.x >> 6;
    int c   = threadIdx.x & 63;
    int pid = blockIdx.x * 4 + w;
    int b   = pid >> 10;
    int n   = pid & 1023;
    int h   = c >> 4, d = c & 15;
    int bh  = b * 4 + h;

    __shared__ float sf[4][64];

    float a = 0.f, ls = 0.f;
    #pragma unroll
    for (int s = 0; s < KSPL; ++s) {
        size_t ro = (size_t)(s * 64 + bh) * 1024 + n;
        a  += apart[(ro << 4) + d];
        ls += lpart[ro];
    }
    sf[w][c] = (a / ls) * pm1[b * 64 + c];
    __syncthreads();

    float acc = bo[c];
    #pragma unroll 8
    for (int i = 0; i < 64; ++i) acc = fmaf(sf[w][i], Wo[i * 64 + c], acc);
    out[(size_t)pid * 64 + c] = acc;
}

// ---------------------------------------------------------------------------
extern "C" void kernel_launch(void* const* d_in, const int* in_sizes, int n_in,
                              void* d_out, int out_size, void* d_ws, size_t ws_size,
                              hipStream_t stream)
{
    const float* desc = (const float*)d_in[0];
    const float* fm   = (const float*)d_in[1];
    const int*   crd  = (const int*)  d_in[2];
    const float* pe   = (const float*)d_in[3];
    const float* Wq   = (const float*)d_in[4];
    const float* bq   = (const float*)d_in[5];
    const float* Wk   = (const float*)d_in[6];
    const float* bk   = (const float*)d_in[7];
    const float* Wv   = (const float*)d_in[8];
    const float* bv   = (const float*)d_in[9];
    const float* Wp   = (const float*)d_in[10];
    const float* bp   = (const float*)d_in[11];
    const float* Wo   = (const float*)d_in[12];
    const float* bo   = (const float*)d_in[13];
    float* out = (float*)d_out;

    float* ws    = (float*)d_ws;
    float* Qb    = ws + OFF_Q;
    float* Kb    = ws + OFF_K;
    float* Vb    = ws + OFF_V;
    float* lpart = ws + OFF_L;
    float* apart = ws + OFF_AT;
    float* pm1   = ws + OFF_PM;
    float* TP    = ws + OFF_TP;

    if (ws_size >= NEED_FULL) {
        // A: parallel transpose to pixel-major, then coalesced 25-tap gather.
        hipLaunchKernelGGL(k_tpose, dim3(BB * 256), dim3(256), 0, stream, fm, TP);
        hipLaunchKernelGGL(k_pf_qkv4, dim3(BB * NN / 4), dim3(256), 0, stream,
                           desc, TP, crd, Wq, bq, Wk, bk, Wv, bv, Qb, Kb, Vb);
    } else {
        hipLaunchKernelGGL(k_pf_qkv, dim3(BB * NN / 4), dim3(256), 0, stream,
                           desc, fm, crd, Wq, bq, Wk, bk, Wv, bv, Qb, Kb, Vb);
    }
    hipLaunchKernelGGL(k_pose, dim3(BB), dim3(64), 0, stream, pe, Wp, bp, pm1);
    hipLaunchKernelGGL(k_attn3, dim3(64 * KSPL), dim3(256), 0, stream,
                       Qb, Kb, Vb, lpart, apart);
    hipLaunchKernelGGL(k_out, dim3(BB * NN / 4), dim3(256), 0, stream,
                       lpart, apart, pm1, Wo, bo, out);
}

// Round 5
// 601.974 us; speedup vs baseline: 1.4708x; 1.0305x over previous
//
#include <hip/hip_runtime.h>
#include <hip/hip_bf16.h>
#include <cstdint>
#include <cstddef>

#define BB 16
#define NN 1024
#define DD 64
#define NHH 4
#define HDD 16
#define KSPL 8   // key splits for attention (128 keys per split)

// workspace layout (in floats)
#define OFF_Q  0
#define OFF_K  (OFF_Q + BB*NHH*NN*HDD)                   // 1,048,576 each
#define OFF_V  (OFF_K + BB*NHH*NN*HDD)
#define OFF_L  (OFF_V + BB*NHH*NN*HDD)                   // KSPL*64*1024
#define OFF_AT (OFF_L + KSPL*64*NN)
#define OFF_PM (OFF_AT + (size_t)KSPL*64*NN*HDD)
#define OFF_TP (OFF_PM + 1024)                            // 16*256*256*64 floats
#define NEED_FULL  ((size_t)(OFF_TP + (size_t)BB*256*256*DD) * 4)

// ---------------------------------------------------------------------------
// A: transpose fm (B,C,H,W) -> TP (B,H*W,C). MLP-optimized:
// thread = (pixel px=t>>2, c-quarter cq=t&3). 16 INDEPENDENT scalar loads
// (all in flight), pack to 4 float4, 4 stores. Store wave-instr = 16 pixels
// x 64B contiguous = 16 full lines (1KB). Load wave-instr = 4 planes x 64B
// full lines. Grid = 16384 blocks.
__global__ __launch_bounds__(256) void k_tpose2(
    const float* __restrict__ fm, float* __restrict__ TP)
{
    int t   = threadIdx.x;
    int pxl = t >> 2, cq = t & 3;
    int bid = blockIdx.x;
    int b   = bid >> 10;
    int pb  = bid & 1023;
    size_t pxg = (size_t)pb * 64 + pxl;

    const float* src = fm + ((size_t)b << 22);
    float*       dst = TP + ((size_t)b << 22) + pxg * 64;

    float4 vals[4];
    #pragma unroll
    for (int j = 0; j < 4; ++j) {
        int c0 = (cq + 4 * j) * 4;
        vals[j].x = src[((size_t)(c0 + 0) << 16) + pxg];
        vals[j].y = src[((size_t)(c0 + 1) << 16) + pxg];
        vals[j].z = src[((size_t)(c0 + 2) << 16) + pxg];
        vals[j].w = src[((size_t)(c0 + 3) << 16) + pxg];
    }
    #pragma unroll
    for (int j = 0; j < 4; ++j)
        *(float4*)(dst + (cq + 4 * j) * 4) = vals[j];
}

// ---------------------------------------------------------------------------
// B: 25-tap patch mean from pixel-major TP (coalesced: lane = channel, one
// pixel = 256B contiguous) + Q/K/V projections. 4 points/block (wave each).
// Coords are point-uniform -> bounds branches wave-uniform.
__global__ __launch_bounds__(256) void k_pf_qkv4(
    const float* __restrict__ desc, const float* __restrict__ TP,
    const int* __restrict__ coords,
    const float* __restrict__ Wq, const float* __restrict__ bq,
    const float* __restrict__ Wk, const float* __restrict__ bk,
    const float* __restrict__ Wv, const float* __restrict__ bv,
    float* __restrict__ Q, float* __restrict__ K, float* __restrict__ V)
{
    int w   = threadIdx.x >> 6;
    int c   = threadIdx.x & 63;
    int pid = blockIdx.x * 4 + w;
    int b   = pid >> 10;
    int n   = pid & 1023;

    __shared__ float spf[4][64];
    __shared__ float sd[4][64];

    int y = coords[pid * 2 + 0];
    int x = coords[pid * 2 + 1];

    const float* tp = TP + ((size_t)b << 22) + c;
    float s = 0.f;
    #pragma unroll
    for (int dy = -2; dy <= 2; ++dy) {
        int yy = y + dy;
        if ((unsigned)yy < 256u) {
            const float* rp = tp + ((size_t)yy << 14);
            #pragma unroll
            for (int dx = -2; dx <= 2; ++dx) {
                int xx = x + dx;
                if ((unsigned)xx < 256u) s += rp[(size_t)xx << 6];
            }
        }
    }
    spf[w][c] = s * 0.04f;
    sd[w][c]  = desc[(size_t)pid * 64 + c];
    __syncthreads();

    float aq = bq[c], ak = bk[c], av = bv[c];
    #pragma unroll 8
    for (int i = 0; i < 64; ++i) {
        float xd = sd[w][i];
        float xp = spf[w][i];
        aq = fmaf(xd, Wq[i * 64 + c], aq);
        ak = fmaf(xp, Wk[i * 64 + c], ak);
        av = fmaf(xp, Wv[i * 64 + c], av);
    }
    int h = c >> 4, d = c & 15;
    size_t o = (((size_t)b * 4 + h) * 1024 + n) * 16 + d;   // (B,NH,N,hd)
    Q[o] = aq; K[o] = ak; V[o] = av;
}

// ---------------------------------------------------------------------------
// B-fallback: original 25-tap gather from channel-major fm (ws too small).
__global__ __launch_bounds__(256) void k_pf_qkv(
    const float* __restrict__ desc, const float* __restrict__ fm,
    const int* __restrict__ coords,
    const float* __restrict__ Wq, const float* __restrict__ bq,
    const float* __restrict__ Wk, const float* __restrict__ bk,
    const float* __restrict__ Wv, const float* __restrict__ bv,
    float* __restrict__ Q, float* __restrict__ K, float* __restrict__ V)
{
    int w   = threadIdx.x >> 6;
    int c   = threadIdx.x & 63;
    int pid = blockIdx.x * 4 + w;
    int b   = pid >> 10;
    int n   = pid & 1023;

    __shared__ float spf[4][64];
    __shared__ float sd[4][64];

    int y = coords[pid * 2 + 0];
    int x = coords[pid * 2 + 1];

    const float* fmc = fm + ((size_t)(b * 64 + c) << 16);
    float s = 0.f;
    #pragma unroll
    for (int dy = -2; dy <= 2; ++dy) {
        int yy = y + dy;
        if ((unsigned)yy < 256u) {
            const float* row = fmc + yy * 256;
            #pragma unroll
            for (int dx = -2; dx <= 2; ++dx) {
                int xx = x + dx;
                if ((unsigned)xx < 256u) s += row[xx];
            }
        }
    }
    spf[w][c] = s * 0.04f;
    sd[w][c]  = desc[(size_t)pid * 64 + c];
    __syncthreads();

    float aq = bq[c], ak = bk[c], av = bv[c];
    #pragma unroll 8
    for (int i = 0; i < 64; ++i) {
        float xd = sd[w][i];
        float xp = spf[w][i];
        aq = fmaf(xd, Wq[i * 64 + c], aq);
        ak = fmaf(xp, Wk[i * 64 + c], ak);
        av = fmaf(xp, Wv[i * 64 + c], av);
    }
    int h = c >> 4, d = c & 15;
    size_t o = (((size_t)b * 4 + h) * 1024 + n) * 16 + d;
    Q[o] = aq; K[o] = ak; V[o] = av;
}

// ---------------------------------------------------------------------------
// K2: pm1[b][c] = 1 + (pose_embed @ Wp + bp)
__global__ __launch_bounds__(64) void k_pose(
    const float* __restrict__ pe, const float* __restrict__ Wp,
    const float* __restrict__ bp, float* __restrict__ pm1)
{
    int b = blockIdx.x, c = threadIdx.x;
    __shared__ float sp[64];
    sp[c] = pe[b * 64 + c];
    __syncthreads();
    float acc = bp[c];
    #pragma unroll 8
    for (int i = 0; i < 64; ++i) acc = fmaf(sp[i], Wp[i * 64 + c], acc);
    pm1[b * 64 + c] = 1.f + acc;
}

// ---------------------------------------------------------------------------
// K3: attention, shift-free softmax. 4 query rows per thread; K/V rows read
// with wave-uniform addresses (scalarizable, no LDS). grid = 64bh*8s = 512.
__global__ __launch_bounds__(256, 2) void k_attn3(
    const float* __restrict__ Q, const float* __restrict__ K,
    const float* __restrict__ V,
    float* __restrict__ lpart, float* __restrict__ apart)
{
    int s  = blockIdx.x & 7;
    int bh = blockIdx.x >> 3;            // 0..63
    int t  = threadIdx.x;

    const float4* Kb = ((const float4*)K) + ((size_t)bh << 12) + ((size_t)s << 9);
    const float4* Vb = ((const float4*)V) + ((size_t)bh << 12) + ((size_t)s << 9);

    float4 q[4][4];
    float4 A[4][4];
    float  l[4];
    #pragma unroll
    for (int i = 0; i < 4; ++i) {
        const float4* qp = ((const float4*)Q) + (((size_t)bh << 10) + t + 256 * i) * 4;
        #pragma unroll
        for (int j = 0; j < 4; ++j) { q[i][j] = qp[j]; A[i][j] = make_float4(0.f,0.f,0.f,0.f); }
        l[i] = 0.f;
    }

    for (int m = 0; m < 128; ++m) {
        float4 ka = Kb[m*4+0], kb = Kb[m*4+1], kc = Kb[m*4+2], kd = Kb[m*4+3];
        float4 va = Vb[m*4+0], vb = Vb[m*4+1], vc = Vb[m*4+2], vd = Vb[m*4+3];
        #pragma unroll
        for (int i = 0; i < 4; ++i) {
            float sc = q[i][0].x*ka.x + q[i][0].y*ka.y + q[i][0].z*ka.z + q[i][0].w*ka.w
                     + q[i][1].x*kb.x + q[i][1].y*kb.y + q[i][1].z*kb.z + q[i][1].w*kb.w
                     + q[i][2].x*kc.x + q[i][2].y*kc.y + q[i][2].z*kc.z + q[i][2].w*kc.w
                     + q[i][3].x*kd.x + q[i][3].y*kd.y + q[i][3].z*kd.z + q[i][3].w*kd.w;
            float p = __expf(sc * 0.25f);     // scores bounded ~|3|: no max-shift
            l[i] += p;
            A[i][0].x = fmaf(p, va.x, A[i][0].x); A[i][0].y = fmaf(p, va.y, A[i][0].y);
            A[i][0].z = fmaf(p, va.z, A[i][0].z); A[i][0].w = fmaf(p, va.w, A[i][0].w);
            A[i][1].x = fmaf(p, vb.x, A[i][1].x); A[i][1].y = fmaf(p, vb.y, A[i][1].y);
            A[i][1].z = fmaf(p, vb.z, A[i][1].z); A[i][1].w = fmaf(p, vb.w, A[i][1].w);
            A[i][2].x = fmaf(p, vc.x, A[i][2].x); A[i][2].y = fmaf(p, vc.y, A[i][2].y);
            A[i][2].z = fmaf(p, vc.z, A[i][2].z); A[i][2].w = fmaf(p, vc.w, A[i][2].w);
            A[i][3].x = fmaf(p, vd.x, A[i][3].x); A[i][3].y = fmaf(p, vd.y, A[i][3].y);
            A[i][3].z = fmaf(p, vd.z, A[i][3].z); A[i][3].w = fmaf(p, vd.w, A[i][3].w);
        }
    }

    #pragma unroll
    for (int i = 0; i < 4; ++i) {
        size_t ro = (size_t)(s * 64 + bh) * 1024 + (t + 256 * i);
        lpart[ro] = l[i];
        float4* ap = (float4*)apart + ro * 4;
        ap[0] = A[i][0]; ap[1] = A[i][1]; ap[2] = A[i][2]; ap[3] = A[i][3];
    }
}

// ---------------------------------------------------------------------------
// K4: combine split-K partials, softmax divide, pose modulation, @ Wo + bo.
__global__ __launch_bounds__(256) void k_out(
    const float* __restrict__ lpart, const float* __restrict__ apart,
    const float* __restrict__ pm1, const float* __restrict__ Wo,
    const float* __restrict__ bo, float* __restrict__ out)
{
    int w   = threadIdx.x >> 6;
    int c   = threadIdx.x & 63;
    int pid = blockIdx.x * 4 + w;
    int b   = pid >> 10;
    int n   = pid & 1023;
    int h   = c >> 4, d = c & 15;
    int bh  = b * 4 + h;

    __shared__ float sf[4][64];

    float a = 0.f, ls = 0.f;
    #pragma unroll
    for (int s = 0; s < KSPL; ++s) {
        size_t ro = (size_t)(s * 64 + bh) * 1024 + n;
        a  += apart[(ro << 4) + d];
        ls += lpart[ro];
    }
    sf[w][c] = (a / ls) * pm1[b * 64 + c];
    __syncthreads();

    float acc = bo[c];
    #pragma unroll 8
    for (int i = 0; i < 64; ++i) acc = fmaf(sf[w][i], Wo[i * 64 + c], acc);
    out[(size_t)pid * 64 + c] = acc;
}

// ---------------------------------------------------------------------------
extern "C" void kernel_launch(void* const* d_in, const int* in_sizes, int n_in,
                              void* d_out, int out_size, void* d_ws, size_t ws_size,
                              hipStream_t stream)
{
    const float* desc = (const float*)d_in[0];
    const float* fm   = (const float*)d_in[1];
    const int*   crd  = (const int*)  d_in[2];
    const float* pe   = (const float*)d_in[3];
    const float* Wq   = (const float*)d_in[4];
    const float* bq   = (const float*)d_in[5];
    const float* Wk   = (const float*)d_in[6];
    const float* bk   = (const float*)d_in[7];
    const float* Wv   = (const float*)d_in[8];
    const float* bv   = (const float*)d_in[9];
    const float* Wp   = (const float*)d_in[10];
    const float* bp   = (const float*)d_in[11];
    const float* Wo   = (const float*)d_in[12];
    const float* bo   = (const float*)d_in[13];
    float* out = (float*)d_out;

    float* ws    = (float*)d_ws;
    float* Qb    = ws + OFF_Q;
    float* Kb    = ws + OFF_K;
    float* Vb    = ws + OFF_V;
    float* lpart = ws + OFF_L;
    float* apart = ws + OFF_AT;
    float* pm1   = ws + OFF_PM;
    float* TP    = ws + OFF_TP;

    if (ws_size >= NEED_FULL) {
        // A: MLP-optimized transpose to pixel-major, then coalesced gather.
        hipLaunchKernelGGL(k_tpose2, dim3(BB * 1024), dim3(256), 0, stream, fm, TP);
        hipLaunchKernelGGL(k_pf_qkv4, dim3(BB * NN / 4), dim3(256), 0, stream,
                           desc, TP, crd, Wq, bq, Wk, bk, Wv, bv, Qb, Kb, Vb);
    } else {
        hipLaunchKernelGGL(k_pf_qkv, dim3(BB * NN / 4), dim3(256), 0, stream,
                           desc, fm, crd, Wq, bq, Wk, bk, Wv, bv, Qb, Kb, Vb);
    }
    hipLaunchKernelGGL(k_pose, dim3(BB), dim3(64), 0, stream, pe, Wp, bp, pm1);
    hipLaunchKernelGGL(k_attn3, dim3(64 * KSPL), dim3(256), 0, stream,
                       Qb, Kb, Vb, lpart, apart);
    hipLaunchKernelGGL(k_out, dim3(BB * NN / 4), dim3(256), 0, stream,
                       lpart, apart, pm1, Wo, bo, out);
}